// Round 3
// baseline (464.263 us; speedup 1.0000x reference)
//
#include <hip/hip_runtime.h>

#define NPG  256   // nodes per graph
#define EPG  4096  // edges per graph
#define FDIM 128
#define KTOP 30
#define NT   1024  // 16 waves -> 4 waves/SIMD for latency hiding

__global__ __launch_bounds__(NT)
void dgcnn_fused(const float* __restrict__ node_feat,
                 const int* __restrict__ srcv, const int* __restrict__ dstv,
                 const int* __restrict__ degs,
                 const float* __restrict__ W0, const float* __restrict__ b0,
                 const float* __restrict__ W1, const float* __restrict__ b1,
                 const float* __restrict__ W2, const float* __restrict__ b2,
                 const float* __restrict__ W3, const float* __restrict__ b3,
                 const float* __restrict__ cw1, const float* __restrict__ cb1,
                 const float* __restrict__ cw2, const float* __restrict__ cb2,
                 const float* __restrict__ ow,  const float* __restrict__ ob,
                 float* __restrict__ outp)
{
    __shared__ float Buf[NPG * 33];          // 33792 B; stride 33 -> bank (n+c)%32
    __shared__ unsigned short srclist[EPG];  // 8192 B; in-edges grouped by dst
    __shared__ int   offs[NPG];
    __shared__ int   cnt [NPG];
    __shared__ int   degl[NPG];
    __shared__ float invd[NPG];
    __shared__ float keys[NPG];
    __shared__ float sbuf[NPG];
    // total ~47.2 KB

    const int g  = blockIdx.x;
    const int t  = threadIdx.x;
    const int n  = t & (NPG - 1);   // node
    const int q  = t >> 8;          // channel quarter 0..3 (wave-uniform)
    const int c0 = q * 8;

    // ================= degrees + exclusive scan (threads < 256) =================
    if (t < NPG) {
        int dn = degs[g * NPG + t];
        degl[t] = dn;
        cnt[t]  = 0;
        invd[t] = 1.0f / (float)(dn + 1);
        offs[t] = dn;
    }
    __syncthreads();
    for (int s = 1; s < NPG; s <<= 1) {
        int v = 0;
        if (t < NPG && t >= s) v = offs[t - s];
        __syncthreads();
        if (t < NPG) offs[t] += v;
        __syncthreads();
    }
    if (t < NPG) offs[t] -= degl[t];   // exclusive prefix
    __syncthreads();

    // ================= edge-list build (counting sort by dst) =================
    {
        const int4* sg4 = (const int4*)(srcv + g * EPG);
        const int4* dg4 = (const int4*)(dstv + g * EPG);
        int4 s4 = sg4[t];
        int4 d4 = dg4[t];
        int ss[4] = {s4.x, s4.y, s4.z, s4.w};
        int dd[4] = {d4.x, d4.y, d4.z, d4.w};
        #pragma unroll
        for (int i = 0; i < 4; i++) {
            int sl = ss[i] & (NPG - 1);   // graphs are 256-node aligned
            int dl = dd[i] & (NPG - 1);
            int p  = atomicAdd(&cnt[dl], 1);
            srclist[offs[dl] + p] = (unsigned short)sl;
        }
    }

    // ================= phase 0: y0 = node_feat @ W0 (8 out-ch per thread) ======
    float acc[8];
    #pragma unroll
    for (int c = 0; c < 8; c++) acc[c] = 0.f;
    {
        const float* nf = node_feat + (size_t)g * NPG * FDIM;
        for (int kc = 0; kc < 4; kc++) {
            __syncthreads();   // Buf chunk reuse
            // stage [256 nodes x 32 k] chunk: 2048 float4, 2 per thread, coalesced
            #pragma unroll
            for (int i = 0; i < 2; i++) {
                int f  = t + i * NT;       // 0..2047
                int nn = f >> 3, k4 = f & 7;
                float4 v = *(const float4*)(nf + nn * FDIM + kc * 32 + k4 * 4);
                float* p = &Buf[nn * 33 + k4 * 4];
                p[0] = v.x; p[1] = v.y; p[2] = v.z; p[3] = v.w;
            }
            __syncthreads();
            const float* wbase = W0 + (kc * 32) * 32 + c0;
            #pragma unroll
            for (int k = 0; k < 32; k++) {
                float hk = Buf[n * 33 + k];        // conflict-free (stride 33)
                const float* wr = wbase + k * 32;  // wave-uniform -> scalar loads
                #pragma unroll
                for (int c = 0; c < 8; c++) acc[c] = fmaf(hk, wr[c], acc[c]);
            }
        }
    }
    __syncthreads();
    #pragma unroll
    for (int c = 0; c < 8; c++) Buf[n * 33 + c0 + c] = acc[c];   // y0
    __syncthreads();

    const int   o  = offs[n];
    const int   d  = degl[n];
    const float iv = invd[n];

    // pooled slice: dst8 = Buf[n][c0..c0+8] + sum_edges Buf[src][c0..c0+8]
    auto gather8 = [&](float (&dst8)[8]) {
        #pragma unroll
        for (int c = 0; c < 8; c++) dst8[c] = Buf[n * 33 + c0 + c];
        int j = 0;
        for (; j + 3 < d; j += 4) {
            int a0 = srclist[o + j],     a1 = srclist[o + j + 1];
            int a2 = srclist[o + j + 2], a3 = srclist[o + j + 3];
            const float* r0 = &Buf[a0 * 33 + c0];
            const float* r1 = &Buf[a1 * 33 + c0];
            const float* r2 = &Buf[a2 * 33 + c0];
            const float* r3 = &Buf[a3 * 33 + c0];
            #pragma unroll
            for (int c = 0; c < 8; c++) dst8[c] += (r0[c] + r1[c]) + (r2[c] + r3[c]);
        }
        for (; j < d; j++) {
            const float* r = &Buf[srclist[o + j] * 33 + c0];
            #pragma unroll
            for (int c = 0; c < 8; c++) dst8[c] += r[c];
        }
    };

    float h1s[8], h2s[8], h3s[8];

    // ---- layer 0: pooled0 already has W0 applied (linearity); bias post-pool ----
    gather8(h1s);
    #pragma unroll
    for (int c = 0; c < 8; c++) h1s[c] = tanhf((h1s[c] + b0[c0 + c]) * iv);
    __syncthreads();   // all gather reads of Buf(y0) done
    #pragma unroll
    for (int c = 0; c < 8; c++) Buf[n * 33 + c0 + c] = h1s[c];
    __syncthreads();

    // ---- layers 1,2: pool h, then apply W to the pooled row ----
    auto layer32 = [&](const float* Wn, const float* bb, float (&hs)[8]) {
        float p8[8];
        gather8(p8);
        __syncthreads();   // all gather reads done
        #pragma unroll
        for (int c = 0; c < 8; c++) Buf[n * 33 + c0 + c] = p8[c];   // pooled row
        __syncthreads();
        float y[8];
        #pragma unroll
        for (int c = 0; c < 8; c++) y[c] = 0.f;
        #pragma unroll
        for (int k = 0; k < 32; k++) {
            float pk = Buf[n * 33 + k];           // own full pooled row
            const float* wr = Wn + k * 32 + c0;   // wave-uniform -> scalar loads
            #pragma unroll
            for (int c = 0; c < 8; c++) y[c] = fmaf(pk, wr[c], y[c]);
        }
        #pragma unroll
        for (int c = 0; c < 8; c++) hs[c] = tanhf((y[c] + bb[c0 + c]) * iv);
        __syncthreads();   // all full-row reads done
        #pragma unroll
        for (int c = 0; c < 8; c++) Buf[n * 33 + c0 + c] = hs[c];
        __syncthreads();
    };
    layer32(W1, b1, h2s);
    layer32(W2, b2, h3s);

    // ---- layer 3: project h3 -> scalar FIRST (linearity), pool scalars ----
    if (t < NPG) {
        float s = 0.f;
        #pragma unroll
        for (int k = 0; k < 32; k++) s = fmaf(Buf[t * 33 + k], W3[k], s);
        sbuf[t] = s;
    }
    __syncthreads();
    if (t < NPG) {
        float s = sbuf[t];
        int oo = offs[t], d2 = degl[t];
        for (int j = 0; j < d2; j++) s += sbuf[srclist[oo + j]];
        keys[t] = tanhf((s + b3[0]) * invd[t]);
    }
    __syncthreads();

    // ================= sortpool: rank-based top-K (jax tie-break: lower idx) ====
    float kv = keys[n];
    int rank = 0;
    #pragma unroll 4
    for (int j = 0; j < NPG; j++) {
        float vj = keys[j];   // uniform address -> broadcast
        rank += ((vj > kv) || ((vj == kv) && (j < n))) ? 1 : 0;
    }

    // ================= export selected Z rows (overlay tail arrays on Buf) ======
    float* sp    = Buf;           // 2910 floats
    float* x1    = Buf + 2910;    // 480
    float* xp    = x1 + 480;      // 240
    float* dense = xp + 240;      // 352   (3982 <= 8448 floats of Buf)

    if (rank < KTOP) {
        float* dp = sp + rank * 97;
        #pragma unroll
        for (int c = 0; c < 8; c++) {
            dp[c0 + c]      = h1s[c];
            dp[32 + c0 + c] = h2s[c];
            dp[64 + c0 + c] = h3s[c];
        }
        if (q == 0) dp[96] = kv;
    }
    __syncthreads();

    // conv1: kernel width 97, stride 97 -> per-row dot; out [16][30], relu
    if (t < 480) {
        int k = t >> 4, c = t & 15;
        float s = cb1[c];
        for (int dd = 0; dd < 97; dd++) s = fmaf(sp[k * 97 + dd], cw1[c * 97 + dd], s);
        x1[c * 30 + k] = fmaxf(s, 0.f);
    }
    __syncthreads();
    // maxpool1d(2,2) -> [16][15]
    if (t < 240) {
        int c = t / 15, k = t - c * 15;
        xp[t] = fmaxf(x1[c * 30 + 2 * k], x1[c * 30 + 2 * k + 1]);
    }
    __syncthreads();
    // conv2: [32][16][5] VALID over 15 -> [32][11], relu; dense idx = c*11+j
    if (t < 352) {
        int c = t / 11, j = t - c * 11;
        float s = cb2[c];
        for (int i2 = 0; i2 < 16; i2++) {
            #pragma unroll
            for (int tt = 0; tt < 5; tt++)
                s = fmaf(xp[i2 * 15 + j + tt], cw2[(c * 16 + i2) * 5 + tt], s);
        }
        dense[t] = fmaxf(s, 0.f);
    }
    __syncthreads();
    // output: relu(relu(dense @ out_w + out_b)) -> [2]
    if (t < 64) {
        float a0 = 0.f, a1 = 0.f;
        for (int dd = t; dd < 352; dd += 64) {
            float v = dense[dd];
            a0 = fmaf(v, ow[dd * 2],     a0);
            a1 = fmaf(v, ow[dd * 2 + 1], a1);
        }
        #pragma unroll
        for (int off2 = 32; off2 > 0; off2 >>= 1) {
            a0 += __shfl_down(a0, off2);
            a1 += __shfl_down(a1, off2);
        }
        if (t == 0) {
            outp[g * 2 + 0] = fmaxf(a0 + ob[0], 0.f);
            outp[g * 2 + 1] = fmaxf(a1 + ob[1], 0.f);
        }
    }
}

extern "C" void kernel_launch(void* const* d_in, const int* in_sizes, int n_in,
                              void* d_out, int out_size, void* d_ws, size_t ws_size,
                              hipStream_t stream) {
    const float* node_feat = (const float*)d_in[0];
    const int*   src       = (const int*)  d_in[1];
    const int*   dst       = (const int*)  d_in[2];
    const int*   degsp     = (const int*)  d_in[3];
    const float* W0 = (const float*)d_in[4];
    const float* b0 = (const float*)d_in[5];
    const float* W1 = (const float*)d_in[6];
    const float* b1 = (const float*)d_in[7];
    const float* W2 = (const float*)d_in[8];
    const float* b2 = (const float*)d_in[9];
    const float* W3 = (const float*)d_in[10];
    const float* b3 = (const float*)d_in[11];
    const float* cw1 = (const float*)d_in[12];
    const float* cb1 = (const float*)d_in[13];
    const float* cw2 = (const float*)d_in[14];
    const float* cb2 = (const float*)d_in[15];
    const float* ow  = (const float*)d_in[16];
    const float* ob  = (const float*)d_in[17];

    dgcnn_fused<<<dim3(256), dim3(NT), 0, stream>>>(
        node_feat, src, dst, degsp,
        W0, b0, W1, b1, W2, b2, W3, b3,
        cw1, cb1, cw2, cb2, ow, ob, (float*)d_out);
}

// Round 4
// 459.116 us; speedup vs baseline: 1.0112x; 1.0112x over previous
//
#include <hip/hip_runtime.h>

#define NPG  256   // nodes per graph
#define EPG  4096  // edges per graph
#define FDIM 128
#define KTOP 30
#define NT   1024  // 16 waves -> 4 waves/SIMD for latency hiding

// (NT, 4): 4 waves/EU min => exactly 1 block/CU, VGPR cap 128/wave.
// Round 3 omitted the 2nd arg -> compiler capped at 64 VGPR and spilled
// 1.1 GB/launch to scratch (FETCH 700MB WRITE 380MB, 464 us).
__global__ __launch_bounds__(NT, 4)
void dgcnn_fused(const float* __restrict__ node_feat,
                 const int* __restrict__ srcv, const int* __restrict__ dstv,
                 const int* __restrict__ degs,
                 const float* __restrict__ W0, const float* __restrict__ b0,
                 const float* __restrict__ W1, const float* __restrict__ b1,
                 const float* __restrict__ W2, const float* __restrict__ b2,
                 const float* __restrict__ W3, const float* __restrict__ b3,
                 const float* __restrict__ cw1, const float* __restrict__ cb1,
                 const float* __restrict__ cw2, const float* __restrict__ cb2,
                 const float* __restrict__ ow,  const float* __restrict__ ob,
                 float* __restrict__ outp)
{
    __shared__ float Buf[NPG * 33];          // 33792 B; stride 33 -> bank (n+c)%32
    __shared__ unsigned short srclist[EPG];  // 8192 B; in-edges grouped by dst
    __shared__ int   offs[NPG];
    __shared__ int   cnt [NPG];
    __shared__ int   degl[NPG];
    __shared__ float invd[NPG];
    __shared__ float keys[NPG];
    __shared__ float sbuf[NPG];
    // total ~47.2 KB

    const int g  = blockIdx.x;
    const int t  = threadIdx.x;
    const int n  = t & (NPG - 1);   // node
    const int q  = t >> 8;          // channel quarter 0..3 (wave-uniform)
    const int c0 = q * 8;

    // ================= degrees + exclusive scan (threads < 256) =================
    if (t < NPG) {
        int dn = degs[g * NPG + t];
        degl[t] = dn;
        cnt[t]  = 0;
        invd[t] = 1.0f / (float)(dn + 1);
        offs[t] = dn;
    }
    __syncthreads();
    for (int s = 1; s < NPG; s <<= 1) {
        int v = 0;
        if (t < NPG && t >= s) v = offs[t - s];
        __syncthreads();
        if (t < NPG) offs[t] += v;
        __syncthreads();
    }
    if (t < NPG) offs[t] -= degl[t];   // exclusive prefix
    __syncthreads();

    // ================= edge-list build (counting sort by dst) =================
    {
        const int4* sg4 = (const int4*)(srcv + g * EPG);
        const int4* dg4 = (const int4*)(dstv + g * EPG);
        int4 s4 = sg4[t];
        int4 d4 = dg4[t];
        int ss[4] = {s4.x, s4.y, s4.z, s4.w};
        int dd[4] = {d4.x, d4.y, d4.z, d4.w};
        #pragma unroll
        for (int i = 0; i < 4; i++) {
            int sl = ss[i] & (NPG - 1);   // graphs are 256-node aligned
            int dl = dd[i] & (NPG - 1);
            int p  = atomicAdd(&cnt[dl], 1);
            srclist[offs[dl] + p] = (unsigned short)sl;
        }
    }

    // ================= phase 0: y0 = node_feat @ W0 (8 out-ch per thread) ======
    float acc[8];
    #pragma unroll
    for (int c = 0; c < 8; c++) acc[c] = 0.f;
    {
        const float* nf = node_feat + (size_t)g * NPG * FDIM;
        for (int kc = 0; kc < 4; kc++) {
            __syncthreads();   // Buf chunk reuse
            // stage [256 nodes x 32 k] chunk: 2048 float4, 2 per thread, coalesced
            #pragma unroll
            for (int i = 0; i < 2; i++) {
                int f  = t + i * NT;       // 0..2047
                int nn = f >> 3, k4 = f & 7;
                float4 v = *(const float4*)(nf + nn * FDIM + kc * 32 + k4 * 4);
                float* p = &Buf[nn * 33 + k4 * 4];
                p[0] = v.x; p[1] = v.y; p[2] = v.z; p[3] = v.w;
            }
            __syncthreads();
            const float* wbase = W0 + (kc * 32) * 32 + c0;
            #pragma unroll
            for (int k = 0; k < 32; k++) {
                float hk = Buf[n * 33 + k];        // conflict-free (stride 33)
                const float* wr = wbase + k * 32;  // wave-uniform -> scalar loads
                #pragma unroll
                for (int c = 0; c < 8; c++) acc[c] = fmaf(hk, wr[c], acc[c]);
            }
        }
    }
    __syncthreads();
    #pragma unroll
    for (int c = 0; c < 8; c++) Buf[n * 33 + c0 + c] = acc[c];   // y0
    __syncthreads();

    const int   o  = offs[n];
    const int   d  = degl[n];
    const float iv = invd[n];

    // pooled slice: dst8 = Buf[n][c0..c0+8] + sum_edges Buf[src][c0..c0+8]
    auto gather8 = [&](float (&dst8)[8]) {
        #pragma unroll
        for (int c = 0; c < 8; c++) dst8[c] = Buf[n * 33 + c0 + c];
        int j = 0;
        for (; j + 3 < d; j += 4) {
            int a0 = srclist[o + j],     a1 = srclist[o + j + 1];
            int a2 = srclist[o + j + 2], a3 = srclist[o + j + 3];
            const float* r0 = &Buf[a0 * 33 + c0];
            const float* r1 = &Buf[a1 * 33 + c0];
            const float* r2 = &Buf[a2 * 33 + c0];
            const float* r3 = &Buf[a3 * 33 + c0];
            #pragma unroll
            for (int c = 0; c < 8; c++) dst8[c] += (r0[c] + r1[c]) + (r2[c] + r3[c]);
        }
        for (; j < d; j++) {
            const float* r = &Buf[srclist[o + j] * 33 + c0];
            #pragma unroll
            for (int c = 0; c < 8; c++) dst8[c] += r[c];
        }
    };

    float h1s[8], h2s[8], h3s[8];

    // ---- layer 0: pooled0 already has W0 applied (linearity); bias post-pool ----
    gather8(h1s);
    #pragma unroll
    for (int c = 0; c < 8; c++) h1s[c] = tanhf((h1s[c] + b0[c0 + c]) * iv);
    __syncthreads();   // all gather reads of Buf(y0) done
    #pragma unroll
    for (int c = 0; c < 8; c++) Buf[n * 33 + c0 + c] = h1s[c];
    __syncthreads();

    // ---- layers 1,2: pool h, then apply W to the pooled row ----
    auto layer32 = [&](const float* Wn, const float* bb, float (&hs)[8]) {
        float p8[8];
        gather8(p8);
        __syncthreads();   // all gather reads done
        #pragma unroll
        for (int c = 0; c < 8; c++) Buf[n * 33 + c0 + c] = p8[c];   // pooled row
        __syncthreads();
        float y[8];
        #pragma unroll
        for (int c = 0; c < 8; c++) y[c] = 0.f;
        #pragma unroll
        for (int k = 0; k < 32; k++) {
            float pk = Buf[n * 33 + k];           // own full pooled row
            const float* wr = Wn + k * 32 + c0;   // wave-uniform -> scalar loads
            #pragma unroll
            for (int c = 0; c < 8; c++) y[c] = fmaf(pk, wr[c], y[c]);
        }
        #pragma unroll
        for (int c = 0; c < 8; c++) hs[c] = tanhf((y[c] + bb[c0 + c]) * iv);
        __syncthreads();   // all full-row reads done
        #pragma unroll
        for (int c = 0; c < 8; c++) Buf[n * 33 + c0 + c] = hs[c];
        __syncthreads();
    };
    layer32(W1, b1, h2s);
    layer32(W2, b2, h3s);

    // ---- layer 3: project h3 -> scalar FIRST (linearity), pool scalars ----
    if (t < NPG) {
        float s = 0.f;
        #pragma unroll
        for (int k = 0; k < 32; k++) s = fmaf(Buf[t * 33 + k], W3[k], s);
        sbuf[t] = s;
    }
    __syncthreads();
    if (t < NPG) {
        float s = sbuf[t];
        int oo = offs[t], d2 = degl[t];
        for (int j = 0; j < d2; j++) s += sbuf[srclist[oo + j]];
        keys[t] = tanhf((s + b3[0]) * invd[t]);
    }
    __syncthreads();

    // ================= sortpool: rank-based top-K (jax tie-break: lower idx) ====
    float kv = keys[n];
    int rank = 0;
    #pragma unroll 4
    for (int j = 0; j < NPG; j++) {
        float vj = keys[j];   // uniform address -> broadcast
        rank += ((vj > kv) || ((vj == kv) && (j < n))) ? 1 : 0;
    }

    // ================= export selected Z rows (overlay tail arrays on Buf) ======
    float* sp    = Buf;           // 2910 floats
    float* x1    = Buf + 2910;    // 480
    float* xp    = x1 + 480;      // 240
    float* dense = xp + 240;      // 352   (3982 <= 8448 floats of Buf)

    if (rank < KTOP) {
        float* dp = sp + rank * 97;
        #pragma unroll
        for (int c = 0; c < 8; c++) {
            dp[c0 + c]      = h1s[c];
            dp[32 + c0 + c] = h2s[c];
            dp[64 + c0 + c] = h3s[c];
        }
        if (q == 0) dp[96] = kv;
    }
    __syncthreads();

    // conv1: kernel width 97, stride 97 -> per-row dot; out [16][30], relu
    if (t < 480) {
        int k = t >> 4, c = t & 15;
        float s = cb1[c];
        for (int dd = 0; dd < 97; dd++) s = fmaf(sp[k * 97 + dd], cw1[c * 97 + dd], s);
        x1[c * 30 + k] = fmaxf(s, 0.f);
    }
    __syncthreads();
    // maxpool1d(2,2) -> [16][15]
    if (t < 240) {
        int c = t / 15, k = t - c * 15;
        xp[t] = fmaxf(x1[c * 30 + 2 * k], x1[c * 30 + 2 * k + 1]);
    }
    __syncthreads();
    // conv2: [32][16][5] VALID over 15 -> [32][11], relu; dense idx = c*11+j
    if (t < 352) {
        int c = t / 11, j = t - c * 11;
        float s = cb2[c];
        for (int i2 = 0; i2 < 16; i2++) {
            #pragma unroll
            for (int tt = 0; tt < 5; tt++)
                s = fmaf(xp[i2 * 15 + j + tt], cw2[(c * 16 + i2) * 5 + tt], s);
        }
        dense[t] = fmaxf(s, 0.f);
    }
    __syncthreads();
    // output: relu(relu(dense @ out_w + out_b)) -> [2]
    if (t < 64) {
        float a0 = 0.f, a1 = 0.f;
        for (int dd = t; dd < 352; dd += 64) {
            float v = dense[dd];
            a0 = fmaf(v, ow[dd * 2],     a0);
            a1 = fmaf(v, ow[dd * 2 + 1], a1);
        }
        #pragma unroll
        for (int off2 = 32; off2 > 0; off2 >>= 1) {
            a0 += __shfl_down(a0, off2);
            a1 += __shfl_down(a1, off2);
        }
        if (t == 0) {
            outp[g * 2 + 0] = fmaxf(a0 + ob[0], 0.f);
            outp[g * 2 + 1] = fmaxf(a1 + ob[1], 0.f);
        }
    }
}

extern "C" void kernel_launch(void* const* d_in, const int* in_sizes, int n_in,
                              void* d_out, int out_size, void* d_ws, size_t ws_size,
                              hipStream_t stream) {
    const float* node_feat = (const float*)d_in[0];
    const int*   src       = (const int*)  d_in[1];
    const int*   dst       = (const int*)  d_in[2];
    const int*   degsp     = (const int*)  d_in[3];
    const float* W0 = (const float*)d_in[4];
    const float* b0 = (const float*)d_in[5];
    const float* W1 = (const float*)d_in[6];
    const float* b1 = (const float*)d_in[7];
    const float* W2 = (const float*)d_in[8];
    const float* b2 = (const float*)d_in[9];
    const float* W3 = (const float*)d_in[10];
    const float* b3 = (const float*)d_in[11];
    const float* cw1 = (const float*)d_in[12];
    const float* cb1 = (const float*)d_in[13];
    const float* cw2 = (const float*)d_in[14];
    const float* cb2 = (const float*)d_in[15];
    const float* ow  = (const float*)d_in[16];
    const float* ob  = (const float*)d_in[17];

    dgcnn_fused<<<dim3(256), dim3(NT), 0, stream>>>(
        node_feat, src, dst, degsp,
        W0, b0, W1, b1, W2, b2, W3, b3,
        cw1, cb1, cw2, cb2, ow, ob, (float*)d_out);
}

// Round 5
// 445.560 us; speedup vs baseline: 1.0420x; 1.0304x over previous
//
#include <hip/hip_runtime.h>

#define NPG  256   // nodes per graph
#define EPG  4096  // edges per graph
#define FDIM 128
#define KTOP 30
#define NT   512   // 8 waves, 2/SIMD
#define RS   36    // row stride (floats): 16B-aligned AND bank-even for b128
#define ZROW 256   // zero pad row (degree-divergence padding)

// (512,2): cap = 512/2 = 256 VGPR (mirrors round-2's proven (256,1)->116).
// Round 3/4 (1024 threads) pinned the cap at 64 -> 1.1 GB scratch spill.
__global__ __launch_bounds__(NT, 2)
void dgcnn_fused(const float* __restrict__ node_feat,
                 const int* __restrict__ srcv, const int* __restrict__ dstv,
                 const int* __restrict__ degs,
                 const float* __restrict__ W0, const float* __restrict__ b0,
                 const float* __restrict__ W1, const float* __restrict__ b1,
                 const float* __restrict__ W2, const float* __restrict__ b2,
                 const float* __restrict__ W3, const float* __restrict__ b3,
                 const float* __restrict__ cw1, const float* __restrict__ cb1,
                 const float* __restrict__ cw2, const float* __restrict__ cb2,
                 const float* __restrict__ ow,  const float* __restrict__ ob,
                 float* __restrict__ outp)
{
    __shared__ __attribute__((aligned(16))) float Buf[(NPG + 1) * RS]; // 37008 B
    __shared__ unsigned short srclist[EPG];  // 8192 B; in-edges grouped by dst
    __shared__ int   offs[NPG];
    __shared__ int   cnt [NPG];
    __shared__ int   degl[NPG];
    __shared__ float invd[NPG];
    __shared__ float keys[NPG];
    __shared__ float sbuf[NPG];
    __shared__ int   rnk [NPG];
    // total ~52.3 KB

    const int g = blockIdx.x;
    const int t = threadIdx.x;

    // ================= degrees + exclusive scan =================
    if (t < NPG) {
        int dn = degs[g * NPG + t];
        degl[t] = dn; cnt[t] = 0;
        invd[t] = 1.0f / (float)(dn + 1);
        offs[t] = dn;
    }
    __syncthreads();
    for (int s = 1; s < NPG; s <<= 1) {
        int v = 0;
        if (t < NPG && t >= s) v = offs[t - s];
        __syncthreads();
        if (t < NPG) offs[t] += v;
        __syncthreads();
    }
    if (t < NPG) offs[t] -= degl[t];   // exclusive prefix
    if (t < RS) Buf[ZROW * RS + t] = 0.f;   // zero pad row
    __syncthreads();

    // ================= edge-list build (counting sort by dst) =================
    {
        const int4* sg4 = (const int4*)(srcv + g * EPG);
        const int4* dg4 = (const int4*)(dstv + g * EPG);
        #pragma unroll
        for (int i = 0; i < 2; i++) {
            int4 s4 = sg4[t + i * NT];
            int4 d4 = dg4[t + i * NT];
            int ss[4] = {s4.x, s4.y, s4.z, s4.w};
            int dd[4] = {d4.x, d4.y, d4.z, d4.w};
            #pragma unroll
            for (int u = 0; u < 4; u++) {
                int sl = ss[u] & (NPG - 1);
                int dl = dd[u] & (NPG - 1);
                int p  = atomicAdd(&cnt[dl], 1);
                srclist[offs[dl] + p] = (unsigned short)sl;
            }
        }
    }

    // thread roles
    const int n  = t & (NPG - 1);   // matmul mapping: node
    const int hh = t >> 8;          // 0/1: channel half
    const int cb = hh << 4;         // channel base (0 or 16)
    const int c4  = (t & 7) << 2;   // gather mapping: 4-ch base (0..28)
    const int grp = t >> 3;         // 0..63 node quad
    const int nb  = grp << 2;       // first node of quad

    int   go[4], gd[4];
    float giv[4];
    #pragma unroll
    for (int i = 0; i < 4; i++) { go[i] = offs[nb + i]; gd[i] = degl[nb + i]; giv[i] = invd[nb + i]; }
    int dm = max(max(gd[0], gd[1]), max(gd[2], gd[3]));

    // ================= phase 0: y0 = X @ W0 (thread = (n,hh): 16 out-ch) ======
    float acc[16];
    #pragma unroll
    for (int c = 0; c < 16; c++) acc[c] = 0.f;
    {
        const float* nf = node_feat + (size_t)g * NPG * FDIM;
        for (int kc = 0; kc < 4; kc++) {
            __syncthreads();   // Buf chunk reuse
            #pragma unroll
            for (int i = 0; i < 4; i++) {
                int f  = t + i * NT;          // 0..2047
                int nn = f >> 3, k4 = f & 7;
                float4 v = *(const float4*)(nf + nn * FDIM + kc * 32 + k4 * 4);
                *(float4*)(&Buf[nn * RS + k4 * 4]) = v;   // bank-even b128
            }
            __syncthreads();
            float row[32];
            #pragma unroll
            for (int j = 0; j < 8; j++) {
                float4 v = *(const float4*)(&Buf[n * RS + j * 4]);  // even b128
                row[j*4+0] = v.x; row[j*4+1] = v.y; row[j*4+2] = v.z; row[j*4+3] = v.w;
            }
            const float* wb = W0 + (kc * 32) * 32 + cb;
            #pragma unroll
            for (int k = 0; k < 32; k++) {
                float hk = row[k];
                const float* wr = wb + k * 32;   // wave-uniform -> scalar loads
                #pragma unroll
                for (int c = 0; c < 16; c++) acc[c] = fmaf(hk, wr[c], acc[c]);
            }
        }
    }
    __syncthreads();
    #pragma unroll
    for (int u = 0; u < 4; u++) {
        float4 v = {acc[u*4], acc[u*4+1], acc[u*4+2], acc[u*4+3]};
        *(float4*)(&Buf[n * RS + cb + u * 4]) = v;   // y0
    }
    __syncthreads();

    // pooled quad gather: pool[i] = Buf[nb+i] + sum_edges Buf[src]  (4 ch/lane)
    auto gather = [&](float4 (&pool)[4]) {
        #pragma unroll
        for (int i = 0; i < 4; i++)
            pool[i] = *(const float4*)(&Buf[(nb + i) * RS + c4]);   // self
        for (int j = 0; j < dm; j++) {
            #pragma unroll
            for (int i = 0; i < 4; i++) {
                int a = ZROW;
                if (j < gd[i]) a = (int)srclist[go[i] + j];   // 8-lane broadcast
                float4 r = *(const float4*)(&Buf[a * RS + c4]);  // bank-even b128
                pool[i].x += r.x; pool[i].y += r.y;
                pool[i].z += r.z; pool[i].w += r.w;
            }
        }
    };

    // ---- layer 0: pooled(y0) -> h1 (computed in gather mapping) ----
    {
        float4 p[4];
        gather(p);
        float4 bv = *(const float4*)(b0 + c4);
        __syncthreads();   // all gather reads of y0 done
        #pragma unroll
        for (int i = 0; i < 4; i++) {
            float4 hv;
            hv.x = tanhf((p[i].x + bv.x) * giv[i]);
            hv.y = tanhf((p[i].y + bv.y) * giv[i]);
            hv.z = tanhf((p[i].z + bv.z) * giv[i]);
            hv.w = tanhf((p[i].w + bv.w) * giv[i]);
            *(float4*)(&Buf[(nb + i) * RS + c4]) = hv;   // h1
        }
        __syncthreads();
    }

    float a1[16], a2[16], a3[16];   // Z archive in (n,hh) layout

    // capture a1 = h1[n][cb..cb+15] while it's still in Buf
    #pragma unroll
    for (int j = 0; j < 4; j++) {
        float4 v = *(const float4*)(&Buf[n * RS + cb + j * 4]);
        a1[j*4+0] = v.x; a1[j*4+1] = v.y; a1[j*4+2] = v.z; a1[j*4+3] = v.w;
    }

    // ---- layers 1,2: gather pooled -> write -> matmul+tanh -> write ----
    auto layer = [&](const float* Wn, const float* bn, float (&ar)[16]) {
        float4 p[4];
        gather(p);
        __syncthreads();   // all gather reads done
        #pragma unroll
        for (int i = 0; i < 4; i++)
            *(float4*)(&Buf[(nb + i) * RS + c4]) = p[i];   // pooled rows
        __syncthreads();
        float row[32];
        #pragma unroll
        for (int j = 0; j < 8; j++) {
            float4 v = *(const float4*)(&Buf[n * RS + j * 4]);   // own pooled row
            row[j*4+0] = v.x; row[j*4+1] = v.y; row[j*4+2] = v.z; row[j*4+3] = v.w;
        }
        float y[16];
        #pragma unroll
        for (int c = 0; c < 16; c++) y[c] = 0.f;
        const float* wb = Wn + cb;
        #pragma unroll
        for (int k = 0; k < 32; k++) {
            float pk = row[k];
            const float* wr = wb + k * 32;   // wave-uniform -> scalar loads
            #pragma unroll
            for (int c = 0; c < 16; c++) y[c] = fmaf(pk, wr[c], y[c]);
        }
        float ivn = invd[n];
        #pragma unroll
        for (int c = 0; c < 16; c++) ar[c] = tanhf((y[c] + bn[cb + c]) * ivn);
        __syncthreads();   // all pooled-row reads done
        #pragma unroll
        for (int u = 0; u < 4; u++) {
            float4 v = {ar[u*4], ar[u*4+1], ar[u*4+2], ar[u*4+3]};
            *(float4*)(&Buf[n * RS + cb + u * 4]) = v;   // h_next
        }
        __syncthreads();
    };
    layer(W1, b1, a2);
    layer(W2, b2, a3);

    // ---- layer 3: project h3 -> scalar (linearity), pool scalars -> keys ----
    if (t < NPG) {
        float s = 0.f;
        #pragma unroll
        for (int j = 0; j < 8; j++) {
            float4 v = *(const float4*)(&Buf[t * RS + j * 4]);
            s = fmaf(v.x, W3[j*4+0], s); s = fmaf(v.y, W3[j*4+1], s);
            s = fmaf(v.z, W3[j*4+2], s); s = fmaf(v.w, W3[j*4+3], s);
        }
        sbuf[t] = s;
    }
    __syncthreads();
    if (t < NPG) {
        float s = sbuf[t];
        int oo = offs[t], d2 = degl[t];
        for (int j = 0; j < d2; j++) s += sbuf[srclist[oo + j]];
        keys[t] = tanhf((s + b3[0]) * invd[t]);
    }
    __syncthreads();

    // ================= sortpool rank (jax tie-break: lower index first) ========
    if (t < NPG) {
        float kvv = keys[t];
        int rr = 0;
        #pragma unroll 4
        for (int j = 0; j < NPG; j++) {
            float vj = keys[j];   // broadcast
            rr += ((vj > kvv) || ((vj == kvv) && (j < t))) ? 1 : 0;
        }
        rnk[t] = rr;
    }
    __syncthreads();

    // ================= export selected Z rows (overlay tail on Buf) ===========
    float* sp    = Buf;           // 2910 floats
    float* x1    = Buf + 2910;    // 480
    float* xp    = x1 + 480;      // 240
    float* dense = xp + 240;      // 352  (3982 <= 9252 floats of Buf)

    {
        int r = rnk[n];
        if (r < KTOP) {
            float* dp = sp + r * 97;
            #pragma unroll
            for (int c = 0; c < 16; c++) {
                dp[cb + c]      = a1[c];
                dp[32 + cb + c] = a2[c];
                dp[64 + cb + c] = a3[c];
            }
            if (hh == 0) dp[96] = keys[n];
        }
    }
    __syncthreads();

    // conv1: kernel width 97, stride 97 -> per-row dot; out [16][30], relu
    if (t < 480) {
        int k = t >> 4, c = t & 15;
        float s = cb1[c];
        for (int dd = 0; dd < 97; dd++) s = fmaf(sp[k * 97 + dd], cw1[c * 97 + dd], s);
        x1[c * 30 + k] = fmaxf(s, 0.f);
    }
    __syncthreads();
    // maxpool1d(2,2) -> [16][15]
    if (t < 240) {
        int c = t / 15, k = t - c * 15;
        xp[t] = fmaxf(x1[c * 30 + 2 * k], x1[c * 30 + 2 * k + 1]);
    }
    __syncthreads();
    // conv2: [32][16][5] VALID over 15 -> [32][11], relu; dense idx = c*11+j
    if (t < 352) {
        int c = t / 11, j = t - c * 11;
        float s = cb2[c];
        for (int i2 = 0; i2 < 16; i2++) {
            #pragma unroll
            for (int tt = 0; tt < 5; tt++)
                s = fmaf(xp[i2 * 15 + j + tt], cw2[(c * 16 + i2) * 5 + tt], s);
        }
        dense[t] = fmaxf(s, 0.f);
    }
    __syncthreads();
    // output: relu(relu(dense @ out_w + out_b)) -> [2]
    if (t < 64) {
        float u0 = 0.f, u1 = 0.f;
        for (int dd = t; dd < 352; dd += 64) {
            float v = dense[dd];
            u0 = fmaf(v, ow[dd * 2],     u0);
            u1 = fmaf(v, ow[dd * 2 + 1], u1);
        }
        #pragma unroll
        for (int off2 = 32; off2 > 0; off2 >>= 1) {
            u0 += __shfl_down(u0, off2);
            u1 += __shfl_down(u1, off2);
        }
        if (t == 0) {
            outp[g * 2 + 0] = fmaxf(u0 + ob[0], 0.f);
            outp[g * 2 + 1] = fmaxf(u1 + ob[1], 0.f);
        }
    }
}

extern "C" void kernel_launch(void* const* d_in, const int* in_sizes, int n_in,
                              void* d_out, int out_size, void* d_ws, size_t ws_size,
                              hipStream_t stream) {
    const float* node_feat = (const float*)d_in[0];
    const int*   src       = (const int*)  d_in[1];
    const int*   dst       = (const int*)  d_in[2];
    const int*   degsp     = (const int*)  d_in[3];
    const float* W0 = (const float*)d_in[4];
    const float* b0 = (const float*)d_in[5];
    const float* W1 = (const float*)d_in[6];
    const float* b1 = (const float*)d_in[7];
    const float* W2 = (const float*)d_in[8];
    const float* b2 = (const float*)d_in[9];
    const float* W3 = (const float*)d_in[10];
    const float* b3 = (const float*)d_in[11];
    const float* cw1 = (const float*)d_in[12];
    const float* cb1 = (const float*)d_in[13];
    const float* cw2 = (const float*)d_in[14];
    const float* cb2 = (const float*)d_in[15];
    const float* ow  = (const float*)d_in[16];
    const float* ob  = (const float*)d_in[17];

    dgcnn_fused<<<dim3(256), dim3(NT), 0, stream>>>(
        node_feat, src, dst, degsp,
        W0, b0, W1, b1, W2, b2, W3, b3,
        cw1, cb1, cw2, cb2, ow, ob, (float*)d_out);
}